// Round 1
// baseline (154.637 us; speedup 1.0000x reference)
//
#include <hip/hip_runtime.h>
#include <math.h>

#define EPSF 1e-12f
#define ATT_NORM_F 4.0f
#define H_DIM 8
#define C_DIM 16
#define N_NODES 100000

// ---------------------------------------------------------------------------
// Pass 1: norm_x[e,h] = sum_c x[e,h,c]^2 ; seg[idx[e],h] = max(...)
// 4 lanes cooperate on one (e,h) row (16 floats = 4 x float4).
// ---------------------------------------------------------------------------
__global__ __launch_bounds__(256) void lip_pass1(
    const float* __restrict__ x, const int* __restrict__ index,
    float* __restrict__ norm_x, unsigned int* __restrict__ seg, int rows)
{
    int tid = blockIdx.x * blockDim.x + threadIdx.x;
    int r = tid >> 2;            // (e,h) row id
    int lane = tid & 3;
    if (r >= rows) return;

    const float4* x4 = (const float4*)x;
    float4 v = x4[(size_t)r * 4 + lane];
    float s = v.x * v.x + v.y * v.y + v.z * v.z + v.w * v.w;
    // reduce across the 4-lane group (groups are aligned within the wave)
    s += __shfl_xor(s, 1);
    s += __shfl_xor(s, 2);

    if (lane == 0) {
        norm_x[r] = s;
        int e = r >> 3;          // r / H_DIM
        int h = r & 7;           // r % H_DIM
        // s >= 0, so float bit pattern is monotone under unsigned compare
        atomicMax(&seg[(size_t)index[e] * H_DIM + h], __float_as_uint(s));
    }
}

// ---------------------------------------------------------------------------
// Pass 2: out[e,h] = alpha[e,h] / (natt[h] * sqrt(seg[idx[e],h] + norm_x[e,h]) + eps)
// One thread handles 4 consecutive heads (float4 everywhere).
// ---------------------------------------------------------------------------
__global__ __launch_bounds__(256) void lip_pass2(
    const float* __restrict__ norm_x, const float* __restrict__ alpha,
    const int* __restrict__ index, const unsigned int* __restrict__ seg,
    const float* __restrict__ att_l, const float* __restrict__ att_r,
    float* __restrict__ out, int total)   // total = E*2
{
    __shared__ float s_natt[H_DIM];
    int t = threadIdx.x;
    if (t < H_DIM) {
        float s = 0.f;
        #pragma unroll
        for (int c = 0; c < C_DIM; ++c) {
            float l = att_l[t * C_DIM + c];
            float r = att_r[t * C_DIM + c];
            s += l * l + r * r;
        }
        s_natt[t] = ATT_NORM_F * sqrtf(s);
    }
    __syncthreads();

    int tid = blockIdx.x * blockDim.x + t;
    if (tid >= total) return;

    int e    = tid >> 1;
    int half = tid & 1;
    int idx  = index[e];

    const float4* nx4 = (const float4*)norm_x;
    const float4* al4 = (const float4*)alpha;
    const float4* sg4 = (const float4*)seg;   // bits are non-negative floats

    float4 nx = nx4[tid];
    float4 al = al4[tid];
    float4 sg = sg4[(size_t)idx * 2 + half];

    int h0 = half * 4;
    float4 o;
    o.x = al.x / (s_natt[h0 + 0] * sqrtf(sg.x + nx.x) + EPSF);
    o.y = al.y / (s_natt[h0 + 1] * sqrtf(sg.y + nx.y) + EPSF);
    o.z = al.z / (s_natt[h0 + 2] * sqrtf(sg.z + nx.z) + EPSF);
    o.w = al.w / (s_natt[h0 + 3] * sqrtf(sg.w + nx.w) + EPSF);
    ((float4*)out)[tid] = o;
}

// ---------------------------------------------------------------------------
// Fallback pass 2 (no norm_x buffer): recompute norm from x, scalar path.
// One thread per (e,h).
// ---------------------------------------------------------------------------
__global__ __launch_bounds__(256) void lip_pass2_recompute(
    const float* __restrict__ x, const float* __restrict__ alpha,
    const int* __restrict__ index, const unsigned int* __restrict__ seg,
    const float* __restrict__ att_l, const float* __restrict__ att_r,
    float* __restrict__ out, int rows)
{
    __shared__ float s_natt[H_DIM];
    int t = threadIdx.x;
    if (t < H_DIM) {
        float s = 0.f;
        #pragma unroll
        for (int c = 0; c < C_DIM; ++c) {
            float l = att_l[t * C_DIM + c];
            float r = att_r[t * C_DIM + c];
            s += l * l + r * r;
        }
        s_natt[t] = ATT_NORM_F * sqrtf(s);
    }
    __syncthreads();

    int r = blockIdx.x * blockDim.x + t;
    if (r >= rows) return;

    const float4* x4 = (const float4*)x;
    float s = 0.f;
    #pragma unroll
    for (int q = 0; q < 4; ++q) {
        float4 v = x4[(size_t)r * 4 + q];
        s += v.x * v.x + v.y * v.y + v.z * v.z + v.w * v.w;
    }
    int e = r >> 3;
    int h = r & 7;
    float sg = __uint_as_float(seg[(size_t)index[e] * H_DIM + h]);
    out[r] = alpha[r] / (s_natt[h] * sqrtf(sg + s) + EPSF);
}

extern "C" void kernel_launch(void* const* d_in, const int* in_sizes, int n_in,
                              void* d_out, int out_size, void* d_ws, size_t ws_size,
                              hipStream_t stream) {
    const float* x     = (const float*)d_in[0];
    const float* att_l = (const float*)d_in[1];
    const float* att_r = (const float*)d_in[2];
    const float* alpha = (const float*)d_in[3];
    const int*   index = (const int*)d_in[4];
    // d_in[5] is num_nodes (device scalar); N is fixed by the problem.

    const int E    = in_sizes[4];
    const int rows = E * H_DIM;

    size_t seg_bytes = (size_t)N_NODES * H_DIM * sizeof(unsigned int);
    size_t seg_pad   = (seg_bytes + 255) / 256 * 256;
    size_t need      = seg_pad + (size_t)rows * sizeof(float);

    unsigned int* seg = (unsigned int*)d_ws;
    hipMemsetAsync(seg, 0, seg_bytes, stream);

    if (ws_size >= need) {
        float* norm_x = (float*)((char*)d_ws + seg_pad);
        int t1 = rows * 4;
        lip_pass1<<<(t1 + 255) / 256, 256, 0, stream>>>(x, index, norm_x, seg, rows);
        int t2 = E * 2;
        lip_pass2<<<(t2 + 255) / 256, 256, 0, stream>>>(
            norm_x, alpha, index, seg, att_l, att_r, (float*)d_out, t2);
    } else {
        // seg table (3.2 MB) assumed to fit; recompute norms in pass 2.
        int t1 = rows * 4;
        lip_pass1<<<(t1 + 255) / 256, 256, 0, stream>>>(x, index, (float*)d_out, seg, rows);
        lip_pass2_recompute<<<(rows + 255) / 256, 256, 0, stream>>>(
            x, alpha, index, seg, att_l, att_r, (float*)d_out, rows);
    }
}